// Round 9
// baseline (543.420 us; speedup 1.0000x reference)
//
#include <hip/hip_runtime.h>
#include <stdint.h>

#define M_DIM 8192
#define K_DIM 4096
#define N_DIM 4096
#define KB (K_DIM / 2)  // bytes per packed-fp4 row: 2048

typedef unsigned char u8;
typedef unsigned int u32;
typedef int i32x4 __attribute__((ext_vector_type(4)));
typedef int i32x8 __attribute__((ext_vector_type(8)));
typedef float f32x4 __attribute__((ext_vector_type(4)));
typedef float float4v __attribute__((ext_vector_type(4)));
typedef u32 u32x2 __attribute__((ext_vector_type(2)));

// sign(v) as fp4 e2m1 code: +1 -> 0x2, -1 -> 0xA, 0 -> 0x0
__device__ __forceinline__ u32 sign_fp4(float v) {
  return v > 0.0f ? 0x2u : (v < 0.0f ? 0xAu : 0x0u);
}

// pack 4 byte-codes (one per byte of v) into 4 nibbles (16-bit result)
__device__ __forceinline__ u32 pk16(u32 v) {
  return (v & 0xFu) | ((v >> 4) & 0xF0u) | ((v >> 8) & 0xF00u) | ((v >> 12) & 0xF000u);
}

// ---------------- fused preprocessing (unchanged from round 8) ---------------
__global__ void binarize_fused(const float* __restrict__ x, const float* __restrict__ w,
                               u32* __restrict__ xb, u8* __restrict__ wT) {
  const int tid = threadIdx.x;
  const int bid = blockIdx.x;
  const int r3 = bid % 3;
  if (r3 != 2) {
    __shared__ u8 tile[64][68];
    const int wtile = (bid / 3) * 2 + r3;
    const int bn = (wtile & 63) * 64;
    const int bk = (wtile >> 6) * 64;

#pragma unroll
    for (int it = 0; it < 4; ++it) {
      int idx = tid + it * 256;
      int rr = idx >> 4;
      int c = (idx & 15) * 4;
      float4v v = *(const float4v*)&w[(size_t)(bk + rr) * N_DIM + bn + c];
      tile[c + 0][rr] = (u8)sign_fp4(v.x);
      tile[c + 1][rr] = (u8)sign_fp4(v.y);
      tile[c + 2][rr] = (u8)sign_fp4(v.z);
      tile[c + 3][rr] = (u8)sign_fp4(v.w);
    }
    __syncthreads();
    const int rn = tid >> 2;
    const int cbyte = (tid & 3) * 8;
    const u32* trow = (const u32*)&tile[rn][0];
    u32 q0 = trow[cbyte / 2 + 0];
    u32 q1 = trow[cbyte / 2 + 1];
    u32 q2 = trow[cbyte / 2 + 2];
    u32 q3 = trow[cbyte / 2 + 3];
    u32x2 o;
    o.x = pk16(q0) | (pk16(q1) << 16);
    o.y = pk16(q2) | (pk16(q3) << 16);
    *(u32x2*)&wT[(size_t)(bn + rn) * KB + (bk >> 1) + cbyte] = o;
  } else {
    const int n8 = M_DIM * K_DIM / 8;
    int i = (bid / 3) * 256 + tid;
    const int stride = 2048 * 256;
    for (; i < n8; i += stride) {
      float4v v0 = ((const float4v*)x)[2 * i];
      float4v v1 = ((const float4v*)x)[2 * i + 1];
      u32 wd = sign_fp4(v0.x) | (sign_fp4(v0.y) << 4) | (sign_fp4(v0.z) << 8) |
               (sign_fp4(v0.w) << 12) | (sign_fp4(v1.x) << 16) | (sign_fp4(v1.y) << 20) |
               (sign_fp4(v1.z) << 24) | (sign_fp4(v1.w) << 28);
      xb[i] = wd;
    }
  }
}

// ------------------------------------------------------------------
// Cross-iteration-preload 256x256 fp4 GEMM.
// Tile t+1's LDS data is fully landed by iter t's MID {vmcnt(0);barrier}
// (A(t+1) staged early in t; B(t+1) staged in t-1). So iter t's 2nd half
// preloads tile t+1's first operands (a0',b0') under clusters 3/4, and
// iter t+1 opens with MFMA immediately. Every read batch hides under an
// MFMA cluster. 2x-unrolled loop ping-pongs named register sets.
// ------------------------------------------------------------------
#define BM 256
#define BN 256
#define BKB 128           // bytes of K per tile (= 256 fp4 elems)
#define NT (K_DIM / 256)  // 16

__device__ __forceinline__ void gload_lds16(const u8* g, u8* l) {
  __builtin_amdgcn_global_load_lds(
      (const __attribute__((address_space(1))) void*)g,
      (__attribute__((address_space(3))) void*)l, 16, 0, 0);
}

// undef hi half: fp4 f8f6f4 MFMA ignores regs [4:7] of each operand
__device__ __forceinline__ i32x8 pad8(i32x4 v) {
  return __builtin_shufflevector(v, v, 0, 1, 2, 3, -1, -1, -1, -1);
}

// fp4 x fp4, per-lane e8m0 scale byte 0x7F (=1.0), opsel byte 0
__device__ __forceinline__ f32x4 mfma_fp4(i32x4 a, i32x4 b, f32x4 c) {
  return __builtin_amdgcn_mfma_scale_f32_16x16x128_f8f6f4(pad8(a), pad8(b), c, 4, 4, 0, 0x7F, 0,
                                                          0x7F);
}

// One K-tile. AP/BP: preloaded a0,b0 (this tile). AN/BN: preload target
// (next tile's a0,b0). Named registers only (no runtime-indexed arrays).
#define GEMM_BODY(T, AP, BP, AN, BN)                                                     \
  {                                                                                      \
    const int buf_ = (T) & 1;                                                            \
    const u8* As_ = &lds[buf_][wr][0];                                                   \
    const u8* Bs_ = &lds[buf_][2 + (wc >> 1)][0];                                        \
    const u8* AsN_ = &lds[buf_ ^ 1][wr][0];                                              \
    const u8* BsN_ = &lds[buf_ ^ 1][2 + (wc >> 1)][0];                                   \
    i32x4 a1_[4], a2_[4], a3_[4], b1_[4];                                                \
    /* R2: a1(mh0,k1) + b1(*,k1); stage A(T+1) */                                        \
    _Pragma("unroll") for (int m = 0; m < 4; ++m) {                                      \
      int row = m * 16 + l15;                                                            \
      a1_[m] = *(const i32x4*)&As_[row * 128 + ((64 + g4 * 16) ^ ((row & 7) << 4))];     \
    }                                                                                    \
    _Pragma("unroll") for (int n = 0; n < 4; ++n) {                                      \
      int row = brow0 + n * 16 + l15;                                                    \
      b1_[n] = *(const i32x4*)&Bs_[row * 128 + ((64 + g4 * 16) ^ ((row & 7) << 4))];     \
    }                                                                                    \
    if ((T) + 1 < NT) {                                                                  \
      const u8* An_ = Ag + (size_t)bm * KB + ((T) + 1) * BKB;                            \
      stage(buf_ ^ 1, 0, An_);                                                           \
      stage(buf_ ^ 1, 1, An_ + (size_t)128 * KB);                                        \
    }                                                                                    \
    __builtin_amdgcn_sched_barrier(0);                                                   \
    /* cluster 1: AP x BP — operands preloaded, no lgkm stall */                         \
    __builtin_amdgcn_s_setprio(1);                                                       \
    _Pragma("unroll") for (int m = 0; m < 4; ++m)                                        \
        _Pragma("unroll") for (int n = 0; n < 4; ++n)                                    \
            acc[m][n] = mfma_fp4(AP[m], BP[n], acc[m][n]);                               \
    __builtin_amdgcn_s_setprio(0);                                                       \
    __builtin_amdgcn_sched_barrier(0);                                                   \
    /* R3: a2(mh1,k0) */                                                                 \
    _Pragma("unroll") for (int m = 0; m < 4; ++m) {                                      \
      int row = 64 + m * 16 + l15;                                                       \
      a2_[m] = *(const i32x4*)&As_[row * 128 + ((g4 * 16) ^ ((row & 7) << 4))];          \
    }                                                                                    \
    __builtin_amdgcn_sched_barrier(0);                                                   \
    /* cluster 2: a1 x b1 (waits R2; R3 in flight) */                                    \
    __builtin_amdgcn_s_setprio(1);                                                       \
    _Pragma("unroll") for (int m = 0; m < 4; ++m)                                        \
        _Pragma("unroll") for (int n = 0; n < 4; ++n)                                    \
            acc[m][n] = mfma_fp4(a1_[m], b1_[n], acc[m][n]);                             \
    __builtin_amdgcn_s_setprio(0);                                                       \
    /* MID: tile T+1 (A,B) fully landed after this */                                    \
    asm volatile("s_waitcnt vmcnt(0)" ::: "memory");                                     \
    __builtin_amdgcn_s_barrier();                                                        \
    /* stage B(T+2); R4: a3(mh1,k1) */                                                   \
    if ((T) + 2 < NT) {                                                                  \
      const u8* Bn_ = Btg + (size_t)bn * KB + ((T) + 2) * BKB;                           \
      stage(buf_, 2, Bn_);                                                               \
      stage(buf_, 3, Bn_ + (size_t)128 * KB);                                            \
    }                                                                                    \
    _Pragma("unroll") for (int m = 0; m < 4; ++m) {                                      \
      int row = 64 + m * 16 + l15;                                                       \
      a3_[m] = *(const i32x4*)&As_[row * 128 + ((64 + g4 * 16) ^ ((row & 7) << 4))];     \
    }                                                                                    \
    __builtin_amdgcn_sched_barrier(0);                                                   \
    /* cluster 3: a2 x BP (waits R3; R4 in flight) */                                    \
    __builtin_amdgcn_s_setprio(1);                                                       \
    _Pragma("unroll") for (int m = 0; m < 4; ++m)                                        \
        _Pragma("unroll") for (int n = 0; n < 4; ++n)                                    \
            acc[4 + m][n] = mfma_fp4(a2_[m], BP[n], acc[4 + m][n]);                      \
    __builtin_amdgcn_s_setprio(0);                                                       \
    __builtin_amdgcn_sched_barrier(0);                                                   \
    /* R1': preload next tile's a0,b0 from buf^1 (landed at MID) */                      \
    if ((T) + 1 < NT) {                                                                  \
      _Pragma("unroll") for (int m = 0; m < 4; ++m) {                                    \
        int row = m * 16 + l15;                                                          \
        AN[m] = *(const i32x4*)&AsN_[row * 128 + ((g4 * 16) ^ ((row & 7) << 4))];        \
      }                                                                                  \
      _Pragma("unroll") for (int n = 0; n < 4; ++n) {                                    \
        int row = brow0 + n * 16 + l15;                                                  \
        BN[n] = *(const i32x4*)&BsN_[row * 128 + ((g4 * 16) ^ ((row & 7) << 4))];        \
      }                                                                                  \
    }                                                                                    \
    __builtin_amdgcn_sched_barrier(0);                                                   \
    /* cluster 4: a3 x b1 (waits R4; R1' in flight) */                                   \
    __builtin_amdgcn_s_setprio(1);                                                       \
    _Pragma("unroll") for (int m = 0; m < 4; ++m)                                        \
        _Pragma("unroll") for (int n = 0; n < 4; ++n)                                    \
            acc[4 + m][n] = mfma_fp4(a3_[m], b1_[n], acc[4 + m][n]);                     \
    __builtin_amdgcn_s_setprio(0);                                                       \
    __builtin_amdgcn_s_barrier();                                                        \
  }

__global__ __launch_bounds__(512, 2) void gemm_bin_fp4(const u8* __restrict__ Ag,
                                                       const u8* __restrict__ Btg,
                                                       float* __restrict__ C) {
  // slots: 0 = A rows[0,128), 1 = A rows[128,256), 2 = Bt[0,128), 3 = Bt[128,256)
  __shared__ u8 lds[2][4][128 * 128];

  const int tid = threadIdx.x;
  const int lane = tid & 63;
  const int wid = tid >> 6;  // 0..7
  const int wr = wid >> 2;   // 0..1 (M half)
  const int wc = wid & 3;    // 0..3 (N quarter)

  // XCD-aware swizzle, nwg = 512 (divisible by 8 -> bijective)
  const int b = blockIdx.x;
  const int sw = (b & 7) * (gridDim.x >> 3) + (b >> 3);
  const int tiles_n = N_DIM / BN;  // 16
  const int bm = (sw / tiles_n) * BM;
  const int bn = (sw % tiles_n) * BN;

  const int l15 = lane & 15;
  const int g4 = lane >> 4;
  const int brow0 = (wc & 1) * 64;
  const int srow = lane >> 3;                      // 0..7
  const int swz_src = (((lane & 7) ^ srow) << 4);  // pre-swizzled byte col

  auto stage = [&](int buf, int slot, const u8* gbase) {
#pragma unroll
    for (int i = 0; i < 2; ++i) {
      const u8* g = gbase + (size_t)(i * 64 + wid * 8 + srow) * KB + swz_src;
      gload_lds16(g, &lds[buf][slot][(i * 64 + wid * 8) * 128]);
    }
  };

  f32x4 acc[8][4] = {};

  // ---- prologue: tile0 fully + B(1) halves (12 loads) ----
  {
    const u8* Abase = Ag + (size_t)bm * KB;
    const u8* Bbase = Btg + (size_t)bn * KB;
    stage(0, 0, Abase);
    stage(0, 1, Abase + (size_t)128 * KB);
    stage(0, 2, Bbase);
    stage(0, 3, Bbase + (size_t)128 * KB);
    stage(1, 2, Bbase + BKB);
    stage(1, 3, Bbase + (size_t)128 * KB + BKB);
  }
  asm volatile("s_waitcnt vmcnt(4)" ::: "memory");  // tile0 landed; B(1) in flight
  __builtin_amdgcn_s_barrier();

  // preload tile0's a0,b0
  i32x4 a0A[4], b0A[4], a0B[4], b0B[4];
  {
    const u8* As0 = &lds[0][wr][0];
    const u8* Bs0 = &lds[0][2 + (wc >> 1)][0];
#pragma unroll
    for (int m = 0; m < 4; ++m) {
      int row = m * 16 + l15;
      a0A[m] = *(const i32x4*)&As0[row * 128 + ((g4 * 16) ^ ((row & 7) << 4))];
    }
#pragma unroll
    for (int n = 0; n < 4; ++n) {
      int row = brow0 + n * 16 + l15;
      b0A[n] = *(const i32x4*)&Bs0[row * 128 + ((g4 * 16) ^ ((row & 7) << 4))];
    }
  }

  for (int t = 0; t < NT; t += 2) {
    GEMM_BODY(t, a0A, b0A, a0B, b0B);
    GEMM_BODY(t + 1, a0B, b0B, a0A, b0A);
  }

  // ---- epilogue: C/D layout col = lane&15, row = (lane>>4)*4 + reg ----
  const int crow0 = bm + wr * 128;
  const int ccol0 = bn + wc * 64;
#pragma unroll
  for (int m = 0; m < 8; ++m)
#pragma unroll
    for (int n = 0; n < 4; ++n)
#pragma unroll
      for (int j = 0; j < 4; ++j)
        C[(size_t)(crow0 + m * 16 + g4 * 4 + j) * N_DIM + ccol0 + n * 16 + l15] = acc[m][n][j];
}

// -------- naive fallback (only if workspace is too small) --------
__global__ void naive_bin_gemm(const float* __restrict__ X, const float* __restrict__ W,
                               float* __restrict__ C) {
  int j = blockIdx.x * blockDim.x + threadIdx.x;
  int i = blockIdx.y;
  if (j >= N_DIM) return;
  float s = 0.0f;
  for (int k = 0; k < K_DIM; ++k) {
    float xv = X[(size_t)i * K_DIM + k];
    float wv = W[(size_t)k * N_DIM + j];
    float sx = (float)((xv > 0.0f) - (xv < 0.0f));
    float sw = (float)((wv > 0.0f) - (wv < 0.0f));
    s += sx * sw;
  }
  C[(size_t)i * N_DIM + j] = s;
}

extern "C" void kernel_launch(void* const* d_in, const int* in_sizes, int n_in,
                              void* d_out, int out_size, void* d_ws, size_t ws_size,
                              hipStream_t stream) {
  const float* x = (const float*)d_in[0];  // [M][K]
  const float* w = (const float*)d_in[1];  // [K][N]
  float* out = (float*)d_out;              // [M][N]

  const size_t xb_bytes = (size_t)M_DIM * KB;  // 16.8 MB
  const size_t wt_bytes = (size_t)N_DIM * KB;  // 8.4 MB

  if (ws_size >= xb_bytes + wt_bytes) {
    u8* xb = (u8*)d_ws;
    u8* wt = (u8*)((char*)d_ws + xb_bytes);

    binarize_fused<<<6144, 256, 0, stream>>>(x, w, (u32*)xb, wt);

    const int grid = (M_DIM / BM) * (N_DIM / BN);  // 32 * 16 = 512
    gemm_bin_fp4<<<grid, 512, 0, stream>>>(xb, wt, out);
  } else {
    naive_bin_gemm<<<dim3(N_DIM / 256, M_DIM), dim3(256), 0, stream>>>(x, w, out);
  }
}

// Round 10
// 125.717 us; speedup vs baseline: 4.3226x; 4.3226x over previous
//
#include <hip/hip_runtime.h>
#include <stdint.h>

#define M_DIM 8192
#define K_DIM 4096
#define N_DIM 4096
#define KB (K_DIM / 2)  // bytes per packed-fp4 row: 2048

typedef unsigned char u8;
typedef unsigned int u32;
typedef int i32x4 __attribute__((ext_vector_type(4)));
typedef int i32x8 __attribute__((ext_vector_type(8)));
typedef float f32x4 __attribute__((ext_vector_type(4)));
typedef float float4v __attribute__((ext_vector_type(4)));
typedef u32 u32x2 __attribute__((ext_vector_type(2)));

// sign(v) as fp4 e2m1 code: +1 -> 0x2, -1 -> 0xA, 0 -> 0x0
__device__ __forceinline__ u32 sign_fp4(float v) {
  return v > 0.0f ? 0x2u : (v < 0.0f ? 0xAu : 0x0u);
}

// pack 4 byte-codes (one per byte of v) into 4 nibbles (16-bit result)
__device__ __forceinline__ u32 pk16(u32 v) {
  return (v & 0xFu) | ((v >> 4) & 0xF0u) | ((v >> 8) & 0xF00u) | ((v >> 12) & 0xF000u);
}

// ---------------- fused preprocessing (unchanged from round 8) ---------------
__global__ void binarize_fused(const float* __restrict__ x, const float* __restrict__ w,
                               u32* __restrict__ xb, u8* __restrict__ wT) {
  const int tid = threadIdx.x;
  const int bid = blockIdx.x;
  const int r3 = bid % 3;
  if (r3 != 2) {
    __shared__ u8 tile[64][68];
    const int wtile = (bid / 3) * 2 + r3;
    const int bn = (wtile & 63) * 64;
    const int bk = (wtile >> 6) * 64;

#pragma unroll
    for (int it = 0; it < 4; ++it) {
      int idx = tid + it * 256;
      int rr = idx >> 4;
      int c = (idx & 15) * 4;
      float4v v = *(const float4v*)&w[(size_t)(bk + rr) * N_DIM + bn + c];
      tile[c + 0][rr] = (u8)sign_fp4(v.x);
      tile[c + 1][rr] = (u8)sign_fp4(v.y);
      tile[c + 2][rr] = (u8)sign_fp4(v.z);
      tile[c + 3][rr] = (u8)sign_fp4(v.w);
    }
    __syncthreads();
    const int rn = tid >> 2;
    const int cbyte = (tid & 3) * 8;
    const u32* trow = (const u32*)&tile[rn][0];
    u32 q0 = trow[cbyte / 2 + 0];
    u32 q1 = trow[cbyte / 2 + 1];
    u32 q2 = trow[cbyte / 2 + 2];
    u32 q3 = trow[cbyte / 2 + 3];
    u32x2 o;
    o.x = pk16(q0) | (pk16(q1) << 16);
    o.y = pk16(q2) | (pk16(q3) << 16);
    *(u32x2*)&wT[(size_t)(bn + rn) * KB + (bk >> 1) + cbyte] = o;
  } else {
    const int n8 = M_DIM * K_DIM / 8;
    int i = (bid / 3) * 256 + tid;
    const int stride = 2048 * 256;
    for (; i < n8; i += stride) {
      float4v v0 = ((const float4v*)x)[2 * i];
      float4v v1 = ((const float4v*)x)[2 * i + 1];
      u32 wd = sign_fp4(v0.x) | (sign_fp4(v0.y) << 4) | (sign_fp4(v0.z) << 8) |
               (sign_fp4(v0.w) << 12) | (sign_fp4(v1.x) << 16) | (sign_fp4(v1.y) << 20) |
               (sign_fp4(v1.z) << 24) | (sign_fp4(v1.w) << 28);
      xb[i] = wd;
    }
  }
}

// ------------------------------------------------------------------
// Cross-iteration preload (IN-PLACE) 256x256 fp4 GEMM.
// a0/b0 are dead after clusters 1/3, so tile t+1's first operands are
// preloaded INTO THE SAME REGISTERS between clusters 3 and 4 — live set
// identical to the round-8 kernel (no ping-pong duplicates, no spill).
// MID {vmcnt(0); barrier} after cluster 2 lands A(t+1),B(t+1) before the
// R1' preload reads them; plain end barrier (B(t+2)'s slots aren't read
// until after the next MID drain). Every read batch hides under an MFMA
// cluster; each iteration opens with MFMA immediately.
// ------------------------------------------------------------------
#define BM 256
#define BN 256
#define BKB 128           // bytes of K per tile (= 256 fp4 elems)
#define NT (K_DIM / 256)  // 16

__device__ __forceinline__ void gload_lds16(const u8* g, u8* l) {
  __builtin_amdgcn_global_load_lds(
      (const __attribute__((address_space(1))) void*)g,
      (__attribute__((address_space(3))) void*)l, 16, 0, 0);
}

// undef hi half: fp4 f8f6f4 MFMA ignores regs [4:7] of each operand
__device__ __forceinline__ i32x8 pad8(i32x4 v) {
  return __builtin_shufflevector(v, v, 0, 1, 2, 3, -1, -1, -1, -1);
}

// fp4 x fp4, per-lane e8m0 scale byte 0x7F (=1.0), opsel byte 0
__device__ __forceinline__ f32x4 mfma_fp4(i32x4 a, i32x4 b, f32x4 c) {
  return __builtin_amdgcn_mfma_scale_f32_16x16x128_f8f6f4(pad8(a), pad8(b), c, 4, 4, 0, 0x7F, 0,
                                                          0x7F);
}

__global__ __launch_bounds__(512, 2) void gemm_bin_fp4(const u8* __restrict__ Ag,
                                                       const u8* __restrict__ Btg,
                                                       float* __restrict__ C) {
  // slots: 0 = A rows[0,128), 1 = A rows[128,256), 2 = Bt[0,128), 3 = Bt[128,256)
  __shared__ u8 lds[2][4][128 * 128];

  const int tid = threadIdx.x;
  const int lane = tid & 63;
  const int wid = tid >> 6;  // 0..7
  const int wr = wid >> 2;   // 0..1 (M half)
  const int wc = wid & 3;    // 0..3 (N quarter)

  // XCD-aware swizzle, nwg = 512 (divisible by 8 -> bijective)
  const int b = blockIdx.x;
  const int sw = (b & 7) * (gridDim.x >> 3) + (b >> 3);
  const int tiles_n = N_DIM / BN;  // 16
  const int bm = (sw / tiles_n) * BM;
  const int bn = (sw % tiles_n) * BN;

  const int l15 = lane & 15;
  const int g4 = lane >> 4;
  const int brow0 = (wc & 1) * 64;
  const int srow = lane >> 3;                      // 0..7
  const int swz_src = (((lane & 7) ^ srow) << 4);  // pre-swizzled byte col

  auto stage = [&](int buf, int slot, const u8* gbase) {
#pragma unroll
    for (int i = 0; i < 2; ++i) {
      const u8* g = gbase + (size_t)(i * 64 + wid * 8 + srow) * KB + swz_src;
      gload_lds16(g, &lds[buf][slot][(i * 64 + wid * 8) * 128]);
    }
  };

  f32x4 acc[8][4] = {};

  // ---- prologue: tile0 fully + B(1) halves (12 loads) ----
  {
    const u8* Abase = Ag + (size_t)bm * KB;
    const u8* Bbase = Btg + (size_t)bn * KB;
    stage(0, 0, Abase);
    stage(0, 1, Abase + (size_t)128 * KB);
    stage(0, 2, Bbase);
    stage(0, 3, Bbase + (size_t)128 * KB);
    stage(1, 2, Bbase + BKB);
    stage(1, 3, Bbase + (size_t)128 * KB + BKB);
  }
  asm volatile("s_waitcnt vmcnt(4)" ::: "memory");  // tile0 landed; B(1) in flight
  __builtin_amdgcn_s_barrier();

  // preload tile0's a0,b0 (the cross-iteration registers)
  i32x4 a0[4], b0[4];
  {
    const u8* As0 = &lds[0][wr][0];
    const u8* Bs0 = &lds[0][2 + (wc >> 1)][0];
#pragma unroll
    for (int m = 0; m < 4; ++m) {
      int row = m * 16 + l15;
      a0[m] = *(const i32x4*)&As0[row * 128 + ((g4 * 16) ^ ((row & 7) << 4))];
    }
#pragma unroll
    for (int n = 0; n < 4; ++n) {
      int row = brow0 + n * 16 + l15;
      b0[n] = *(const i32x4*)&Bs0[row * 128 + ((g4 * 16) ^ ((row & 7) << 4))];
    }
  }

  for (int t = 0; t < NT; ++t) {
    const int buf = t & 1;
    const u8* As = &lds[buf][wr][0];
    const u8* Bs = &lds[buf][2 + (wc >> 1)][0];
    const u8* AsN = &lds[buf ^ 1][wr][0];
    const u8* BsN = &lds[buf ^ 1][2 + (wc >> 1)][0];

    i32x4 a1[4], a2[4], a3[4], b1[4];

    // ===== R2: a1(mh0,k1) + b1(*,k1); stage A(t+1) into buf^1 =====
#pragma unroll
    for (int m = 0; m < 4; ++m) {
      int row = m * 16 + l15;
      a1[m] = *(const i32x4*)&As[row * 128 + ((64 + g4 * 16) ^ ((row & 7) << 4))];
    }
#pragma unroll
    for (int n = 0; n < 4; ++n) {
      int row = brow0 + n * 16 + l15;
      b1[n] = *(const i32x4*)&Bs[row * 128 + ((64 + g4 * 16) ^ ((row & 7) << 4))];
    }
    if (t + 1 < NT) {
      const u8* An = Ag + (size_t)bm * KB + (t + 1) * BKB;
      stage(buf ^ 1, 0, An);
      stage(buf ^ 1, 1, An + (size_t)128 * KB);
    }
    __builtin_amdgcn_sched_barrier(0);

    // ===== cluster 1: a0 x b0 (preloaded — no lgkm stall) =====
    __builtin_amdgcn_s_setprio(1);
#pragma unroll
    for (int m = 0; m < 4; ++m)
#pragma unroll
      for (int n = 0; n < 4; ++n)
        acc[m][n] = mfma_fp4(a0[m], b0[n], acc[m][n]);
    __builtin_amdgcn_s_setprio(0);
    __builtin_amdgcn_sched_barrier(0);

    // ===== R3: a2(mh1,k0) — overlaps cluster 2's wait =====
#pragma unroll
    for (int m = 0; m < 4; ++m) {
      int row = 64 + m * 16 + l15;
      a2[m] = *(const i32x4*)&As[row * 128 + ((g4 * 16) ^ ((row & 7) << 4))];
    }
    __builtin_amdgcn_sched_barrier(0);

    // ===== cluster 2: a1 x b1 (waits R2; R3 in flight) =====
    __builtin_amdgcn_s_setprio(1);
#pragma unroll
    for (int m = 0; m < 4; ++m)
#pragma unroll
      for (int n = 0; n < 4; ++n)
        acc[m][n] = mfma_fp4(a1[m], b1[n], acc[m][n]);
    __builtin_amdgcn_s_setprio(0);

    // ===== MID: A(t+1) and B(t+1) fully landed after this =====
    asm volatile("s_waitcnt vmcnt(0)" ::: "memory");
    __builtin_amdgcn_s_barrier();

    // ===== stage B(t+2) into buf slots 2-3; R4: a3(mh1,k1) =====
    if (t + 2 < NT) {
      const u8* Bn = Btg + (size_t)bn * KB + (t + 2) * BKB;
      stage(buf, 2, Bn);
      stage(buf, 3, Bn + (size_t)128 * KB);
    }
#pragma unroll
    for (int m = 0; m < 4; ++m) {
      int row = 64 + m * 16 + l15;
      a3[m] = *(const i32x4*)&As[row * 128 + ((64 + g4 * 16) ^ ((row & 7) << 4))];
    }
    __builtin_amdgcn_sched_barrier(0);

    // ===== cluster 3: a2 x b0 (waits R3; R4 in flight) =====
    __builtin_amdgcn_s_setprio(1);
#pragma unroll
    for (int m = 0; m < 4; ++m)
#pragma unroll
      for (int n = 0; n < 4; ++n)
        acc[4 + m][n] = mfma_fp4(a2[m], b0[n], acc[4 + m][n]);
    __builtin_amdgcn_s_setprio(0);
    __builtin_amdgcn_sched_barrier(0);

    // ===== R1': preload tile t+1's a0,b0 IN PLACE (a0 dead since C1,
    //            b0 dead since C3; buf^1 data landed at MID) =====
    if (t + 1 < NT) {
#pragma unroll
      for (int m = 0; m < 4; ++m) {
        int row = m * 16 + l15;
        a0[m] = *(const i32x4*)&AsN[row * 128 + ((g4 * 16) ^ ((row & 7) << 4))];
      }
#pragma unroll
      for (int n = 0; n < 4; ++n) {
        int row = brow0 + n * 16 + l15;
        b0[n] = *(const i32x4*)&BsN[row * 128 + ((g4 * 16) ^ ((row & 7) << 4))];
      }
    }
    __builtin_amdgcn_sched_barrier(0);

    // ===== cluster 4: a3 x b1 (waits R4; R1' in flight) =====
    __builtin_amdgcn_s_setprio(1);
#pragma unroll
    for (int m = 0; m < 4; ++m)
#pragma unroll
      for (int n = 0; n < 4; ++n)
        acc[4 + m][n] = mfma_fp4(a3[m], b1[n], acc[4 + m][n]);
    __builtin_amdgcn_s_setprio(0);

    // end barrier: B(t+2) stays in flight (its slots aren't read until
    // after the NEXT iter's MID vmcnt(0) drain)
    __builtin_amdgcn_s_barrier();
  }

  // ---- epilogue: C/D layout col = lane&15, row = (lane>>4)*4 + reg ----
  const int crow0 = bm + wr * 128;
  const int ccol0 = bn + wc * 64;
#pragma unroll
  for (int m = 0; m < 8; ++m)
#pragma unroll
    for (int n = 0; n < 4; ++n)
#pragma unroll
      for (int j = 0; j < 4; ++j)
        C[(size_t)(crow0 + m * 16 + g4 * 4 + j) * N_DIM + ccol0 + n * 16 + l15] = acc[m][n][j];
}

// -------- naive fallback (only if workspace is too small) --------
__global__ void naive_bin_gemm(const float* __restrict__ X, const float* __restrict__ W,
                               float* __restrict__ C) {
  int j = blockIdx.x * blockDim.x + threadIdx.x;
  int i = blockIdx.y;
  if (j >= N_DIM) return;
  float s = 0.0f;
  for (int k = 0; k < K_DIM; ++k) {
    float xv = X[(size_t)i * K_DIM + k];
    float wv = W[(size_t)k * N_DIM + j];
    float sx = (float)((xv > 0.0f) - (xv < 0.0f));
    float sw = (float)((wv > 0.0f) - (wv < 0.0f));
    s += sx * sw;
  }
  C[(size_t)i * N_DIM + j] = s;
}

extern "C" void kernel_launch(void* const* d_in, const int* in_sizes, int n_in,
                              void* d_out, int out_size, void* d_ws, size_t ws_size,
                              hipStream_t stream) {
  const float* x = (const float*)d_in[0];  // [M][K]
  const float* w = (const float*)d_in[1];  // [K][N]
  float* out = (float*)d_out;              // [M][N]

  const size_t xb_bytes = (size_t)M_DIM * KB;  // 16.8 MB
  const size_t wt_bytes = (size_t)N_DIM * KB;  // 8.4 MB

  if (ws_size >= xb_bytes + wt_bytes) {
    u8* xb = (u8*)d_ws;
    u8* wt = (u8*)((char*)d_ws + xb_bytes);

    binarize_fused<<<6144, 256, 0, stream>>>(x, w, (u32*)xb, wt);

    const int grid = (M_DIM / BM) * (N_DIM / BN);  // 32 * 16 = 512
    gemm_bin_fp4<<<grid, 512, 0, stream>>>(xb, wt, out);
  } else {
    naive_bin_gemm<<<dim3(N_DIM / 256, M_DIM), dim3(256), 0, stream>>>(x, w, out);
  }
}